// Round 12
// baseline (217.707 us; speedup 1.0000x reference)
//
#include <hip/hip_runtime.h>

#define BOUND 1e-6f
#define HALF_PI 1.57079632679489662f
#define LOG2E 1.44269504088896341f

// DPP helper: masked/out-of-range lanes receive `oldv` (1.0 = mult identity).
#define UPD_DPP(oldv, srcv, ctrl, rmask)                                        \
  __int_as_float(__builtin_amdgcn_update_dpp(                                   \
      __float_as_int(oldv), __float_as_int(srcv), (ctrl), (rmask), 0xF, false))

// Inclusive multiplicative scan across 64 lanes, pure VALU (validated R2-R11).
__device__ __forceinline__ float wave_incl_prod(float x) {
    x *= UPD_DPP(1.0f, x, 0x111, 0xF);  // row_shr:1
    x *= UPD_DPP(1.0f, x, 0x112, 0xF);  // row_shr:2
    x *= UPD_DPP(1.0f, x, 0x114, 0xF);  // row_shr:4
    x *= UPD_DPP(1.0f, x, 0x118, 0xF);  // row_shr:8
    x *= UPD_DPP(1.0f, x, 0x142, 0xA);  // row_bcast:15 -> rows 1,3
    x *= UPD_DPP(1.0f, x, 0x143, 0xC);  // row_bcast:31 -> rows 2,3
    return x;
}

// R12: sector-exact wave-autonomous pipeline. Each wave owns 16 consecutive
// rows (16448 B = 257 x 64-B sectors EXACTLY -- per-owner regions stay
// sector-aligned, the R11 bug) processed as 4 groups of 4 rows via a private
// 4112-B LDS slice with depth-1 register prefetch, fully unrolled, ZERO
// barriers (wave-local lgkmcnt only; same-wave DS ops are in-order so slice
// reuse is WAR-safe). Intra-wave group seams are written back-to-back by the
// same wave (L2 write-combines); inter-wave seams are sector-aligned.
// Block = 4 waves x 16 rows; LDS 16448 B -> 8 blocks/CU = 32 waves (full).
// Per-row math identical to R9 (poly sin/cos in u, exp2 sigmoid).
// out[j]   = radius * prod_{i<j}(sin(a_i)+B) * (cos(a_j)+B),  j < 256
// out[256] = radius * prod_{i<256}(sin(a_i)+B)
__global__ __launch_bounds__(256) void spherize_kernel(
    const float* __restrict__ x,
    const float* __restrict__ p_phiL,
    const float* __restrict__ p_radius,
    const float* __restrict__ p_scaling,
    float* __restrict__ out,
    int n_rows)
{
    __shared__ float lds[4 * 1028];   // 4 waves x 1028 dwords (4112 B each)

    const float phi_L  = p_phiL[0];
    const float radius = p_radius[0];
    const float cexp   = p_scaling[0] * LOG2E;  // exp(s*x) = exp2(cexp*x)
    const float amp    = HALF_PI - phi_L;

    const int lane = threadIdx.x & 63;
    const int wave = threadIdx.x >> 6;          // 0..3
    float* myl = lds + wave * 1028;             // this wave's private slice

    const int wrow0 = (blockIdx.x * 4 + wave) * 16;  // wave's first row
    if (wrow0 >= n_rows) return;

    // ---- load group g (4 rows) into registers ----
    auto LOADG = [&](float4 (&r)[4], int g) {
        const int r0 = wrow0 + g * 4;
        const float* xb = x + (size_t)r0 * 256 + lane * 4;
        #pragma unroll
        for (int i = 0; i < 4; ++i)
            if (r0 + i < n_rows)
                r[i] = *reinterpret_cast<const float4*>(xb + i * 256);
    };

    // ---- compute group, stage via private LDS, store 4112 B (no barrier) --
    auto PROC = [&](const float4 (&r)[4], int g) {
        const int r0 = wrow0 + g * 4;
        const int nr = min(4, n_rows - r0);
        if (nr <= 0) return;
        #pragma unroll
        for (int i = 0; i < 4; ++i) {
            if (i >= nr) break;
            const float* xp = &r[i].x;
            float s[4], cc[4];
            #pragma unroll
            for (int k = 0; k < 4; ++k) {
                // u = pi/2 - a = amp / (1 + exp(s*x))
                float e  = __builtin_amdgcn_exp2f(cexp * xp[k]);
                float u  = amp * __builtin_amdgcn_rcpf(1.0f + e);
                float u2 = u * u;
                s[k] = fmaf(u2, fmaf(u2, 4.16666667e-2f, -0.5f), 1.0f + BOUND);
                float p = fmaf(u2, fmaf(u2, 8.33333333e-3f, -1.66666667e-1f), 1.0f);
                cc[k] = fmaf(u, p, BOUND);
            }
            float q1 = s[0];
            float q2 = q1 * s[1];
            float q3 = q2 * s[2];
            float t  = q3 * s[3];
            float scan = wave_incl_prod(t);               // inclusive over lanes
            float excl = UPD_DPP(1.0f, scan, 0x138, 0xF); // wave_shr:1, lane0=1
            float base = radius * excl;

            float* lrow = myl + i * 257 + lane * 4;
            lrow[0] = base * cc[0];
            lrow[1] = base * q1 * cc[1];
            lrow[2] = base * q2 * cc[2];
            lrow[3] = base * q3 * cc[3];
            if (lane == 63)
                lrow[4] = radius * scan;                  // col 256
        }
        // wave-local LDS visibility only; no s_barrier, no vmcnt drain
        asm volatile("s_waitcnt lgkmcnt(0)" ::: "memory");

        float* obase = out + (size_t)r0 * 257;            // 16B-aligned
        if (nr == 4) {
            const float4* l4 = reinterpret_cast<const float4*>(myl);
            float4*       o4 = reinterpret_cast<float4*>(obase);
            o4[lane]       = l4[lane];
            o4[lane + 64]  = l4[lane + 64];
            o4[lane + 128] = l4[lane + 128];
            o4[lane + 192] = l4[lane + 192];
            if (lane == 0) o4[256] = l4[256];
        } else {
            const int nd = nr * 257;
            for (int j = lane; j < nd; j += 64) obase[j] = myl[j];
        }
    };

    // ---- fully-unrolled depth-1 pipeline over the wave's 4 groups ----
    float4 A[4], B[4];
    LOADG(A, 0);
    LOADG(B, 1); PROC(A, 0);
    LOADG(A, 2); PROC(B, 1);
    LOADG(B, 3); PROC(A, 2);
    PROC(B, 3);
}

extern "C" void kernel_launch(void* const* d_in, const int* in_sizes, int n_in,
                              void* d_out, int out_size, void* d_ws, size_t ws_size,
                              hipStream_t stream) {
    // inputs: 0=x [N,256], 1=W_theta, 2=W_phi, 3=b_phi, 4=phi_L, 5=radius, 6=scaling
    const float* x         = (const float*)d_in[0];
    const float* p_phiL    = (const float*)d_in[4];
    const float* p_radius  = (const float*)d_in[5];
    const float* p_scaling = (const float*)d_in[6];
    float* out = (float*)d_out;

    const int n_rows = in_sizes[0] / 256;
    const int blocks = (n_rows + 63) / 64;   // 8192 for N=524288 (64 rows/block)

    spherize_kernel<<<blocks, 256, 0, stream>>>(x, p_phiL, p_radius, p_scaling,
                                                out, n_rows);
}

// Round 14
// 187.116 us; speedup vs baseline: 1.1635x; 1.1635x over previous
//
#include <hip/hip_runtime.h>

#define BOUND 1e-6f
#define HALF_PI 1.57079632679489662f
#define LOG2E 1.44269504088896341f

typedef float f32x4 __attribute__((ext_vector_type(4)));  // clang-native vec4

// DPP helper: masked/out-of-range lanes receive `oldv` (1.0 = mult identity).
#define UPD_DPP(oldv, srcv, ctrl, rmask)                                        \
  __int_as_float(__builtin_amdgcn_update_dpp(                                   \
      __float_as_int(oldv), __float_as_int(srcv), (ctrl), (rmask), 0xF, false))

// Inclusive multiplicative scan across 64 lanes, pure VALU (validated R2-R12).
__device__ __forceinline__ float wave_incl_prod(float x) {
    x *= UPD_DPP(1.0f, x, 0x111, 0xF);  // row_shr:1
    x *= UPD_DPP(1.0f, x, 0x112, 0xF);  // row_shr:2
    x *= UPD_DPP(1.0f, x, 0x114, 0xF);  // row_shr:4
    x *= UPD_DPP(1.0f, x, 0x118, 0xF);  // row_shr:8
    x *= UPD_DPP(1.0f, x, 0x142, 0xA);  // row_bcast:15 -> rows 1,3
    x *= UPD_DPP(1.0f, x, 0x143, 0xC);  // row_bcast:31 -> rows 2,3
    return x;
}

// R14 = R9 (best, 204us) + NON-TEMPORAL global access on both streams
// (R13 intent; fixed: nt builtins need clang-native vector type, not
// HIP_vector_type). R9 structure is forced by the sector model: partial
// 64B-sector writes RMW at write-arrival time, so stores are issued as a
// sector-exact block-coop burst of a 16448B (=257 sectors) region. Both
// streams are strictly streaming (no reuse), so `nt` frees L2 allocate/tag
// bandwidth -- the last structural difference vs the 6.29 TB/s copy ceiling.
// Block = 256 thr (4 waves) x 16 rows; LDS 16448B -> 8 blocks/CU, 32 waves.
// out[j]   = radius * prod_{i<j}(sin(a_i)+B) * (cos(a_j)+B),  j < 256
// out[256] = radius * prod_{i<256}(sin(a_i)+B)
__global__ __launch_bounds__(256) void spherize_kernel(
    const float* __restrict__ x,
    const float* __restrict__ p_phiL,
    const float* __restrict__ p_radius,
    const float* __restrict__ p_scaling,
    float* __restrict__ out,
    int n_rows)
{
    __shared__ float lds[16 * 257];   // 16448 B

    const float phi_L  = p_phiL[0];
    const float radius = p_radius[0];
    const float cexp   = p_scaling[0] * LOG2E;  // exp(s*x) = exp2(cexp*x)
    const float amp    = HALF_PI - phi_L;

    const int tid  = threadIdx.x;
    const int lane = tid & 63;
    const int wave = tid >> 6;              // 0..3
    const int row0 = blockIdx.x * 16;       // block's first row
    const int wrow = row0 + wave * 4;       // this wave's first row

    const int nr_blk = min(16, n_rows - row0);        // rows in this block
    const int nr_w   = min(4, max(0, n_rows - wrow)); // rows for this wave

    // ---- load this wave's 4 rows up front (nt float4, 1KB/instr) ----
    f32x4 xv[4];
    const f32x4* xb =
        reinterpret_cast<const f32x4*>(x + (size_t)wrow * 256 + lane * 4);
    #pragma unroll
    for (int i = 0; i < 4; ++i)
        if (i < nr_w) xv[i] = __builtin_nontemporal_load(xb + i * 64);

    // ---- compute rows into LDS (R9-validated math) ----
    #pragma unroll
    for (int i = 0; i < 4; ++i) {
        if (i >= nr_w) break;
        float s[4], c[4];
        #pragma unroll
        for (int k = 0; k < 4; ++k) {
            // u = pi/2 - a = amp / (1 + exp(s*x))
            float e  = __builtin_amdgcn_exp2f(cexp * xv[i][k]);
            float u  = amp * __builtin_amdgcn_rcpf(1.0f + e);
            float u2 = u * u;
            s[k] = fmaf(u2, fmaf(u2, 4.16666667e-2f, -0.5f), 1.0f + BOUND);
            float p = fmaf(u2, fmaf(u2, 8.33333333e-3f, -1.66666667e-1f), 1.0f);
            c[k] = fmaf(u, p, BOUND);
        }

        // intra-lane prefix products (exclusive prefixes q* come free)
        float q1 = s[0];
        float q2 = q1 * s[1];
        float q3 = q2 * s[2];
        float t  = q3 * s[3];
        float scan = wave_incl_prod(t);               // inclusive over lanes
        float excl = UPD_DPP(1.0f, scan, 0x138, 0xF); // wave_shr:1, lane0=1.0
        float base = radius * excl;

        float* lrow = lds + (wave * 4 + i) * 257 + lane * 4;
        lrow[0] = base * c[0];
        lrow[1] = base * q1 * c[1];
        lrow[2] = base * q2 * c[2];
        lrow[3] = base * q3 * c[3];
        if (lane == 63)
            lrow[4] = radius * scan;                  // col 256: full product
    }
    __syncthreads();

    // ---- cooperative sector-exact nt burst store of the block's region ----
    float* obase = out + (size_t)row0 * 257;
    if (nr_blk == 16) {
        // 16*257 = 4112 dwords = 1028 float4; region = 257 full 64B sectors
        const f32x4* l4 = reinterpret_cast<const f32x4*>(lds);
        f32x4*       o4 = reinterpret_cast<f32x4*>(obase);
        __builtin_nontemporal_store(l4[tid],       o4 + tid);
        __builtin_nontemporal_store(l4[tid + 256], o4 + tid + 256);
        __builtin_nontemporal_store(l4[tid + 512], o4 + tid + 512);
        __builtin_nontemporal_store(l4[tid + 768], o4 + tid + 768);
        if (tid < 4)
            __builtin_nontemporal_store(l4[tid + 1024], o4 + tid + 1024);
    } else {
        // tail block (not hit for N=524288): safe dword cooperative store
        const int nd = nr_blk * 257;
        for (int i = tid; i < nd; i += 256) obase[i] = lds[i];
    }
}

extern "C" void kernel_launch(void* const* d_in, const int* in_sizes, int n_in,
                              void* d_out, int out_size, void* d_ws, size_t ws_size,
                              hipStream_t stream) {
    // inputs: 0=x [N,256], 1=W_theta, 2=W_phi, 3=b_phi, 4=phi_L, 5=radius, 6=scaling
    const float* x         = (const float*)d_in[0];
    const float* p_phiL    = (const float*)d_in[4];
    const float* p_radius  = (const float*)d_in[5];
    const float* p_scaling = (const float*)d_in[6];
    float* out = (float*)d_out;

    const int n_rows = in_sizes[0] / 256;
    const int blocks = (n_rows + 15) / 16;   // 32768 for N=524288

    spherize_kernel<<<blocks, 256, 0, stream>>>(x, p_phiL, p_radius, p_scaling,
                                                out, n_rows);
}